// Round 1
// baseline (379.918 us; speedup 1.0000x reference)
//
#include <hip/hip_runtime.h>
#include <hip/hip_bf16.h>
#include <math.h>

#define B_N 64
#define C_N 512
#define M_N 1024

typedef __attribute__((ext_vector_type(8))) short bf16x8;
typedef __attribute__((ext_vector_type(4))) float f32x4;

__device__ __forceinline__ float b2f(unsigned short u) {
  unsigned int x = ((unsigned int)u) << 16;
  return __builtin_bit_cast(float, x);
}
__device__ __forceinline__ unsigned short f2b(float f) {
  unsigned int x = __builtin_bit_cast(unsigned int, f);
  unsigned int lsb = (x >> 16) & 1u;
  x += 0x7fffu + lsb;
  return (unsigned short)(x >> 16);
}
__device__ __forceinline__ float bround(float f) { return b2f(f2b(f)); }

// ---------- dtype detection: bf16 N(0,1) data -> ~all uint16s look like bf16;
// fp32 data -> low halves have uniform random exponents (~10% plausible). ----
__global__ void k_detect(const unsigned short* __restrict__ p, int* __restrict__ flag) {
  unsigned short u = p[threadIdx.x];
  int e = (u >> 7) & 0xff;
  int pl = (u == 0) || (e >= 110 && e <= 134);
  int cnt = __syncthreads_count(pl);
  if (threadIdx.x == 0) *flag = (cnt >= 208) ? 1 : 0;  // 1 = bf16, 0 = fp32
}

// ---------- positional embedding, stored bf16 [C][M] ----------
__global__ void k_pe(unsigned short* __restrict__ pe) {
  int idx = blockIdx.x * 256 + threadIdx.x;
  int c = idx >> 10, m = idx & 1023;
  // div = exp((2i) * (-ln(10000)/C)), 2i = c & ~1
  float freq = expf((float)(c & ~1) * (-9.210340371976184f / 512.0f));
  float ang = (float)m * freq;
  float v = (c & 1) ? cosf(ang) : sinf(ang);
  pe[idx] = f2b(v);
}

// ---------- row sums: rx = sum_m bf16(h+pe), rb = sum_m h  (fp32 accum) -----
__global__ void k_sums(const void* __restrict__ hin, const unsigned short* __restrict__ pe,
                       const int* __restrict__ flag, float* __restrict__ rx,
                       float* __restrict__ rb) {
  int lane = threadIdx.x & 63;
  int row = blockIdx.x * 4 + (threadIdx.x >> 6);  // row in [0, B*C)
  int c = row & (C_N - 1);
  int f = *flag;
  const unsigned short* per = pe + (size_t)c * M_N;
  float sx = 0.f, sb = 0.f;
  if (f) {
    const unsigned short* h = (const unsigned short*)hin + (size_t)row * M_N;
    for (int j = 0; j < 16; ++j) {
      int m = j * 64 + lane;
      float hv = b2f(h[m]);
      float xv = bround(hv + b2f(per[m]));  // ref rounds x to bf16
      sx += xv; sb += hv;
    }
  } else {
    const float* h = (const float*)hin + (size_t)row * M_N;
    for (int j = 0; j < 16; ++j) {
      int m = j * 64 + lane;
      float hv = h[m];
      sx += hv + b2f(per[m]); sb += hv;
    }
  }
  for (int off = 32; off > 0; off >>= 1) {
    sx += __shfl_down(sx, off);
    sb += __shfl_down(sb, off);
  }
  if (lane == 0) { rx[row] = sx; rb[row] = sb; }
}

// ---------- gate = sigmoid(conv1d_k5(y) . w + b), y = rx/M ----------
__global__ void k_gate(const void* __restrict__ wp, const void* __restrict__ bp,
                       const int* __restrict__ flag, const float* __restrict__ rx,
                       float* __restrict__ gate) {
  int idx = blockIdx.x * 256 + threadIdx.x;  // [0, B*C)
  int b = idx >> 9, c = idx & (C_N - 1);
  int f = *flag;
  float acc = 0.f;
  for (int k = 0; k < 5; ++k) {
    int cc = c + k - 2;
    if (cc < 0 || cc >= C_N) continue;
    float y = rx[b * C_N + cc] * (1.0f / 1024.0f);
    float w;
    if (f) { y = bround(y); w = b2f(((const unsigned short*)wp)[c * 5 + k]); }
    else   { w = ((const float*)wp)[c * 5 + k]; }
    acc += y * w;
  }
  float bias = f ? b2f(((const unsigned short*)bp)[c]) : ((const float*)bp)[c];
  float s = f ? bround(bround(acc) + bias) : (acc + bias);
  float g = 1.0f / (1.0f + expf(-s));
  if (f) g = bround(g);
  gate[idx] = g;
}

// ---------- batched dual Gram + epilogue ----------
// cov[b,c,d] = gc*gd*(S1/M - rxc*rxd/M^2) + (S2/M - rbc*rbd/M^2) + (c==d)*1e-8
// S1 = X X^T, S2 = H H^T, X = bf16(h + pe). 128x128 tile per block, 4 waves,
// each wave a 64x64 quadrant as 4x4 MFMA 16x16x32 tiles. LDS rows padded to 40
// ushorts (80 B = 20 banks -> 2-way alias only, free; keeps 16B alignment).
__global__ __launch_bounds__(256, 2)
void k_cov(const void* __restrict__ hin, const unsigned short* __restrict__ pe,
           const int* __restrict__ flag, const float* __restrict__ rx,
           const float* __restrict__ rb, const float* __restrict__ gate,
           void* __restrict__ out) {
  __shared__ unsigned short sXa[128 * 40];
  __shared__ unsigned short sHa[128 * 40];
  __shared__ unsigned short sXb[128 * 40];
  __shared__ unsigned short sHb[128 * 40];

  int t = threadIdx.x;
  int b = blockIdx.z;
  int cblk = blockIdx.y * 128, dblk = blockIdx.x * 128;
  int f = *flag;
  int lane = t & 63, wave = t >> 6;
  int wr = (wave >> 1) * 64, wc = (wave & 1) * 64;
  int fr = lane & 15, fk = (lane >> 4) * 8;
  int sr = t >> 1, sc = (t & 1) * 16;  // staging: row, 16-elem chunk

  f32x4 acc1[4][4], acc2[4][4];
  const f32x4 z = {0.f, 0.f, 0.f, 0.f};
  for (int i = 0; i < 4; i++)
    for (int j = 0; j < 4; j++) { acc1[i][j] = z; acc2[i][j] = z; }

  const size_t hb0 = (size_t)b * C_N * M_N;
  const unsigned short* peA = pe + (size_t)(cblk + sr) * M_N + sc;
  const unsigned short* peB = pe + (size_t)(dblk + sr) * M_N + sc;
  const unsigned short* hA16 = (const unsigned short*)hin + hb0 + (size_t)(cblk + sr) * M_N + sc;
  const unsigned short* hB16 = (const unsigned short*)hin + hb0 + (size_t)(dblk + sr) * M_N + sc;
  const float* hA32 = (const float*)hin + hb0 + (size_t)(cblk + sr) * M_N + sc;
  const float* hB32 = (const float*)hin + hb0 + (size_t)(dblk + sr) * M_N + sc;

  union U { uint4 v[2]; unsigned short u[16]; };

  for (int kk = 0; kk < M_N; kk += 32) {
    U pa, pb, wxa, wha, wxb, whb;
    {
      const uint4* ppa = reinterpret_cast<const uint4*>(peA + kk);
      pa.v[0] = ppa[0]; pa.v[1] = ppa[1];
      const uint4* ppb = reinterpret_cast<const uint4*>(peB + kk);
      pb.v[0] = ppb[0]; pb.v[1] = ppb[1];
    }
    if (f) {
      U ua, ub;
      const uint4* qa = reinterpret_cast<const uint4*>(hA16 + kk);
      ua.v[0] = qa[0]; ua.v[1] = qa[1];
      const uint4* qb = reinterpret_cast<const uint4*>(hB16 + kk);
      ub.v[0] = qb[0]; ub.v[1] = qb[1];
      for (int e = 0; e < 16; e++) {
        wha.u[e] = ua.u[e];
        whb.u[e] = ub.u[e];
        wxa.u[e] = f2b(b2f(ua.u[e]) + b2f(pa.u[e]));
        wxb.u[e] = f2b(b2f(ub.u[e]) + b2f(pb.u[e]));
      }
    } else {
      float fa[16], fb[16];
      const float4* qa = reinterpret_cast<const float4*>(hA32 + kk);
      const float4* qb = reinterpret_cast<const float4*>(hB32 + kk);
      for (int e = 0; e < 4; e++) {
        float4 va = qa[e], vb = qb[e];
        fa[4 * e + 0] = va.x; fa[4 * e + 1] = va.y; fa[4 * e + 2] = va.z; fa[4 * e + 3] = va.w;
        fb[4 * e + 0] = vb.x; fb[4 * e + 1] = vb.y; fb[4 * e + 2] = vb.z; fb[4 * e + 3] = vb.w;
      }
      for (int e = 0; e < 16; e++) {
        wha.u[e] = f2b(fa[e]);
        whb.u[e] = f2b(fb[e]);
        wxa.u[e] = f2b(fa[e] + b2f(pa.u[e]));
        wxb.u[e] = f2b(fb[e] + b2f(pb.u[e]));
      }
    }
    {
      uint4* d0 = reinterpret_cast<uint4*>(&sXa[sr * 40 + sc]);
      d0[0] = wxa.v[0]; d0[1] = wxa.v[1];
      uint4* d1 = reinterpret_cast<uint4*>(&sHa[sr * 40 + sc]);
      d1[0] = wha.v[0]; d1[1] = wha.v[1];
      uint4* d2 = reinterpret_cast<uint4*>(&sXb[sr * 40 + sc]);
      d2[0] = wxb.v[0]; d2[1] = wxb.v[1];
      uint4* d3 = reinterpret_cast<uint4*>(&sHb[sr * 40 + sc]);
      d3[0] = whb.v[0]; d3[1] = whb.v[1];
    }
    __syncthreads();

    bf16x8 bX[4], bH[4];
    for (int j = 0; j < 4; j++) {
      int dr = wc + j * 16 + fr;
      bX[j] = *reinterpret_cast<const bf16x8*>(&sXb[dr * 40 + fk]);
      bH[j] = *reinterpret_cast<const bf16x8*>(&sHb[dr * 40 + fk]);
    }
    for (int i = 0; i < 4; i++) {
      int cr = wr + i * 16 + fr;
      bf16x8 aX = *reinterpret_cast<const bf16x8*>(&sXa[cr * 40 + fk]);
      bf16x8 aH = *reinterpret_cast<const bf16x8*>(&sHa[cr * 40 + fk]);
      for (int j = 0; j < 4; j++) {
        acc1[i][j] = __builtin_amdgcn_mfma_f32_16x16x32_bf16(aX, bX[j], acc1[i][j], 0, 0, 0);
        acc2[i][j] = __builtin_amdgcn_mfma_f32_16x16x32_bf16(aH, bH[j], acc2[i][j], 0, 0, 0);
      }
    }
    __syncthreads();
  }

  // epilogue
  const float invM = 1.0f / 1024.0f;
  const float invM2 = invM * invM;
  const float* gb = gate + b * C_N;
  const float* rxb = rx + b * C_N;
  const float* rbb = rb + b * C_N;
  for (int i = 0; i < 4; i++) {
    for (int r = 0; r < 4; r++) {
      int c = cblk + wr + i * 16 + (lane >> 4) * 4 + r;
      float gc = gb[c], rxc = rxb[c], rbc = rbb[c];
      for (int j = 0; j < 4; j++) {
        int d = dblk + wc + j * 16 + (lane & 15);
        float v = gc * gb[d] * (acc1[i][j][r] * invM - rxc * rxb[d] * invM2)
                + (acc2[i][j][r] * invM - rbc * rbb[d] * invM2);
        if (c == d) v += 1e-8f;
        size_t o = ((size_t)b * C_N + c) * C_N + d;
        if (f) ((unsigned short*)out)[o] = f2b(v);
        else   ((float*)out)[o] = v;
      }
    }
  }
}

extern "C" void kernel_launch(void* const* d_in, const int* in_sizes, int n_in,
                              void* d_out, int out_size, void* d_ws, size_t ws_size,
                              hipStream_t stream) {
  const void* h_in = d_in[0];
  const void* conv_w = d_in[1];
  const void* conv_b = d_in[2];

  char* ws = (char*)d_ws;
  int* flag = (int*)ws;                                   // 16 B slot
  unsigned short* pe = (unsigned short*)(ws + 16);        // C*M bf16 = 1 MiB
  float* rx = (float*)(ws + 16 + C_N * M_N * 2);          // B*C fp32
  float* rb = rx + B_N * C_N;
  float* gate = rb + B_N * C_N;

  k_detect<<<1, 256, 0, stream>>>((const unsigned short*)h_in, flag);
  k_pe<<<(C_N * M_N) / 256, 256, 0, stream>>>(pe);
  k_sums<<<(B_N * C_N) / 4, 256, 0, stream>>>(h_in, pe, flag, rx, rb);
  k_gate<<<(B_N * C_N) / 256, 256, 0, stream>>>(conv_w, conv_b, flag, rx, gate);
  dim3 g(C_N / 128, C_N / 128, B_N);
  k_cov<<<g, 256, 0, stream>>>(h_in, pe, flag, rx, rb, gate, d_out);
}

// Round 2
// 373.632 us; speedup vs baseline: 1.0168x; 1.0168x over previous
//
#include <hip/hip_runtime.h>
#include <hip/hip_bf16.h>
#include <math.h>

#define B_N 64
#define C_N 512
#define M_N 1024

typedef __attribute__((ext_vector_type(8))) short bf16x8;
typedef __attribute__((ext_vector_type(4))) float f32x4;
typedef __attribute__((ext_vector_type(16))) float f32x16;

__device__ __forceinline__ float b2f(unsigned short u) {
  unsigned int x = ((unsigned int)u) << 16;
  return __builtin_bit_cast(float, x);
}
__device__ __forceinline__ unsigned short f2b(float f) {
  unsigned int x = __builtin_bit_cast(unsigned int, f);
  unsigned int lsb = (x >> 16) & 1u;
  x += 0x7fffu + lsb;
  return (unsigned short)(x >> 16);
}
__device__ __forceinline__ float bround(float f) { return b2f(f2b(f)); }

// async global->LDS, 16B per lane; LDS dest = wave-uniform base + lane*16
typedef __attribute__((address_space(1))) const unsigned int gas_uint;
typedef __attribute__((address_space(3))) unsigned int las_uint;
__device__ __forceinline__ void async_ld(const void* g, const void* l) {
  __builtin_amdgcn_global_load_lds((gas_uint*)(uintptr_t)g,
                                   (las_uint*)(unsigned int)(uintptr_t)l, 16, 0, 0);
}

// ---------- dtype detection ----------
__global__ void k_detect(const unsigned short* __restrict__ p, int* __restrict__ flag) {
  unsigned short u = p[threadIdx.x];
  int e = (u >> 7) & 0xff;
  int pl = (u == 0) || (e >= 110 && e <= 134);
  int cnt = __syncthreads_count(pl);
  if (threadIdx.x == 0) *flag = (cnt >= 208) ? 1 : 0;  // 1 = bf16, 0 = fp32
}

__global__ void k_mode(const int* __restrict__ flag, int wsOK, int* __restrict__ mode) {
  if (threadIdx.x == 0) *mode = (*flag == 1 && wsOK) ? 1 : 0;
}

// ---------- positional embedding, bf16 [C][M] ----------
__global__ void k_pe(unsigned short* __restrict__ pe) {
  int idx = blockIdx.x * 256 + threadIdx.x;
  int c = idx >> 10, m = idx & 1023;
  float freq = expf((float)(c & ~1) * (-9.210340371976184f / 512.0f));
  float ang = (float)m * freq;
  float v = (c & 1) ? cosf(ang) : sinf(ang);
  pe[idx] = f2b(v);
}

// ---------- per-row sums of pe (fp32) ----------
__global__ void k_pesum(const unsigned short* __restrict__ pe, float* __restrict__ pesum) {
  int lane = threadIdx.x & 63;
  int row = blockIdx.x * 4 + (threadIdx.x >> 6);  // 512 rows
  float s = 0.f;
  const uint4* p = (const uint4*)(pe + (size_t)row * M_N);
  for (int j = 0; j < 2; j++) {
    union { uint4 v; unsigned short u[8]; } a; a.v = p[j * 64 + lane];
    for (int k = 0; k < 8; k++) s += b2f(a.u[k]);
  }
  for (int off = 32; off; off >>= 1) s += __shfl_down(s, off);
  if (lane == 0) pesum[row] = s;
}

// ---------- row sums of h (vectorized); rx = rb + pesum[c] ----------
__global__ void k_sums(const void* __restrict__ hin, const int* __restrict__ flag,
                       const float* __restrict__ pesum, float* __restrict__ rx,
                       float* __restrict__ rb) {
  int lane = threadIdx.x & 63;
  int row = blockIdx.x * 4 + (threadIdx.x >> 6);  // [0, B*C)
  int f = *flag;
  float s = 0.f;
  if (f) {
    const uint4* h = (const uint4*)((const unsigned short*)hin + (size_t)row * M_N);
    for (int j = 0; j < 2; j++) {
      union { uint4 v; unsigned short u[8]; } a; a.v = h[j * 64 + lane];
      for (int k = 0; k < 8; k++) s += b2f(a.u[k]);
    }
  } else {
    const float4* h = (const float4*)((const float*)hin + (size_t)row * M_N);
    for (int j = 0; j < 4; j++) {
      float4 v = h[j * 64 + lane];
      s += v.x + v.y + v.z + v.w;
    }
  }
  for (int off = 32; off; off >>= 1) s += __shfl_down(s, off);
  if (lane == 0) { rb[row] = s; rx[row] = s + pesum[row & (C_N - 1)]; }
}

// ---------- gate ----------
__global__ void k_gate(const void* __restrict__ wp, const void* __restrict__ bp,
                       const int* __restrict__ flag, const float* __restrict__ rx,
                       float* __restrict__ gate) {
  int idx = blockIdx.x * 256 + threadIdx.x;  // [0, B*C)
  int b = idx >> 9, c = idx & (C_N - 1);
  int f = *flag;
  float acc = 0.f;
  for (int k = 0; k < 5; ++k) {
    int cc = c + k - 2;
    if (cc < 0 || cc >= C_N) continue;
    float y = rx[b * C_N + cc] * (1.0f / 1024.0f);
    float w;
    if (f) { y = bround(y); w = b2f(((const unsigned short*)wp)[c * 5 + k]); }
    else   { w = ((const float*)wp)[c * 5 + k]; }
    acc += y * w;
  }
  float bias = f ? b2f(((const unsigned short*)bp)[c]) : ((const float*)bp)[c];
  float s = f ? bround(bround(acc) + bias) : (acc + bias);
  float g = 1.0f / (1.0f + expf(-s));
  if (f) g = bround(g);
  gate[idx] = g;
}

// ---------- X = bf16(h + pe), materialized (fast path only) ----------
__global__ void k_prep(const void* __restrict__ hin, const unsigned short* __restrict__ pe,
                       const int* __restrict__ mode, unsigned short* __restrict__ X) {
  if (*mode != 1) return;
  size_t e = ((size_t)blockIdx.x * 256 + threadIdx.x) * 8;
  int cm = (int)(e & ((size_t)C_N * M_N - 1));
  union { uint4 v; unsigned short u[8]; } a, p, r;
  a.v = *(const uint4*)((const unsigned short*)hin + e);
  p.v = *(const uint4*)(pe + cm);
  for (int k = 0; k < 8; k++) r.u[k] = f2b(b2f(a.u[k]) + b2f(p.u[k]));
  *(uint4*)(X + e) = r.v;
}

// ---------- FAST cov: dual-Gram via 32x32x16 MFMA + global_load_lds ----------
// LDS tiles [128][32] bf16, unpadded (global_load_lds needs lane-contiguous).
// XOR swizzle: 16B chunk at (row, pcol) holds data (row, pcol ^ ((row>>1)&3)).
// Fragment reads then spread 64 lanes over 8 bank-groups evenly (conflict-free).
__global__ __launch_bounds__(256, 2)
void k_cov2(const unsigned short* __restrict__ X, const void* __restrict__ hin,
            const int* __restrict__ mode, const float* __restrict__ rx,
            const float* __restrict__ rb, const float* __restrict__ gate,
            void* __restrict__ out) {
  if (*mode != 1) return;
  __shared__ unsigned short tiles[4][128 * 32];  // Xa, Ha, Xb, Hb = 32 KB

  const unsigned short* H = (const unsigned short*)hin;
  int t = threadIdx.x;
  int lane = t & 63, w = t >> 6;
  int b = blockIdx.z;
  int cblk = blockIdx.y * 128, dblk = blockIdx.x * 128;

  // staging: wave w owns tile w (0:Xa 1:Ha 2:Xb 3:Hb)
  const unsigned short* src = (w & 1) ? H : X;
  int rowbase = (w & 2) ? dblk : cblk;
  int gcol = (lane & 3) ^ ((lane >> 3) & 3);  // swizzled source chunk
  const unsigned short* gp = src + (size_t)b * (C_N * M_N)
                           + (size_t)(rowbase + (lane >> 2)) * M_N + gcol * 8;

  int wr = (w >> 1) * 64, wc = (w & 1) * 64;  // 64x64 quadrant
  int fr = lane & 31, L5 = lane >> 5;
  int sw = (fr >> 1) & 3;

  f32x16 a1[2][2], a2[2][2];
  for (int i = 0; i < 2; i++)
    for (int j = 0; j < 2; j++)
      for (int r = 0; r < 16; r++) { a1[i][j][r] = 0.f; a2[i][j][r] = 0.f; }

  for (int kk = 0; kk < M_N; kk += 32) {
    const unsigned short* g0 = gp + kk;
    for (int g = 0; g < 8; g++)
      async_ld(g0 + (size_t)g * (16 * M_N), &tiles[w][g * 512]);
    __syncthreads();

    for (int ks = 0; ks < 2; ks++) {
      int kc = (ks * 2 + L5);
      bf16x8 aX[2], aH[2], bX[2], bH[2];
      for (int i = 0; i < 2; i++) {
        int R = wr + i * 32 + fr;
        int off = R * 32 + (kc ^ sw) * 8;
        aX[i] = *(const bf16x8*)&tiles[0][off];
        aH[i] = *(const bf16x8*)&tiles[1][off];
      }
      for (int j = 0; j < 2; j++) {
        int D = wc + j * 32 + fr;
        int off = D * 32 + (kc ^ sw) * 8;
        bX[j] = *(const bf16x8*)&tiles[2][off];
        bH[j] = *(const bf16x8*)&tiles[3][off];
      }
      for (int i = 0; i < 2; i++)
        for (int j = 0; j < 2; j++) {
          a1[i][j] = __builtin_amdgcn_mfma_f32_32x32x16_bf16(aX[i], bX[j], a1[i][j], 0, 0, 0);
          a2[i][j] = __builtin_amdgcn_mfma_f32_32x32x16_bf16(aH[i], bH[j], a2[i][j], 0, 0, 0);
        }
    }
    __syncthreads();
  }

  // epilogue: C/D map (32x32): col = lane&31, row = (reg&3)+8*(reg>>2)+4*L5
  const float invM = 1.0f / 1024.0f, invM2 = invM * invM;
  const float* gb = gate + b * C_N;
  const float* rxb = rx + b * C_N;
  const float* rbb = rb + b * C_N;
  unsigned short* o16 = (unsigned short*)out;
  for (int i = 0; i < 2; i++)
    for (int j = 0; j < 2; j++) {
      int d = dblk + wc + j * 32 + (lane & 31);
      float gd = gb[d], rxd = rxb[d], rbd = rbb[d];
      for (int reg = 0; reg < 16; reg++) {
        int row = (reg & 3) + 8 * (reg >> 2) + 4 * L5;
        int c = cblk + wr + i * 32 + row;
        float v = gb[c] * gd * (a1[i][j][reg] * invM - rxb[c] * rxd * invM2)
                + (a2[i][j][reg] * invM - rbb[c] * rbd * invM2);
        if (c == d) v += 1e-8f;
        o16[((size_t)b * C_N + c) * C_N + d] = f2b(v);
      }
    }
}

// ---------- SLOW cov (fallback: fp32 input or small ws) ----------
__global__ __launch_bounds__(256, 2)
void k_cov(const void* __restrict__ hin, const unsigned short* __restrict__ pe,
           const int* __restrict__ flag, const int* __restrict__ mode,
           const float* __restrict__ rx, const float* __restrict__ rb,
           const float* __restrict__ gate, void* __restrict__ out) {
  if (*mode != 0) return;
  __shared__ unsigned short sXa[128 * 40];
  __shared__ unsigned short sHa[128 * 40];
  __shared__ unsigned short sXb[128 * 40];
  __shared__ unsigned short sHb[128 * 40];

  int t = threadIdx.x;
  int b = blockIdx.z;
  int cblk = blockIdx.y * 128, dblk = blockIdx.x * 128;
  int f = *flag;
  int lane = t & 63, wave = t >> 6;
  int wr = (wave >> 1) * 64, wc = (wave & 1) * 64;
  int fr = lane & 15, fk = (lane >> 4) * 8;
  int sr = t >> 1, sc = (t & 1) * 16;

  f32x4 acc1[4][4], acc2[4][4];
  const f32x4 z = {0.f, 0.f, 0.f, 0.f};
  for (int i = 0; i < 4; i++)
    for (int j = 0; j < 4; j++) { acc1[i][j] = z; acc2[i][j] = z; }

  const size_t hb0 = (size_t)b * C_N * M_N;
  const unsigned short* peA = pe + (size_t)(cblk + sr) * M_N + sc;
  const unsigned short* peB = pe + (size_t)(dblk + sr) * M_N + sc;
  const unsigned short* hA16 = (const unsigned short*)hin + hb0 + (size_t)(cblk + sr) * M_N + sc;
  const unsigned short* hB16 = (const unsigned short*)hin + hb0 + (size_t)(dblk + sr) * M_N + sc;
  const float* hA32 = (const float*)hin + hb0 + (size_t)(cblk + sr) * M_N + sc;
  const float* hB32 = (const float*)hin + hb0 + (size_t)(dblk + sr) * M_N + sc;

  union U { uint4 v[2]; unsigned short u[16]; };

  for (int kk = 0; kk < M_N; kk += 32) {
    U pa, pb, wxa, wha, wxb, whb;
    {
      const uint4* ppa = reinterpret_cast<const uint4*>(peA + kk);
      pa.v[0] = ppa[0]; pa.v[1] = ppa[1];
      const uint4* ppb = reinterpret_cast<const uint4*>(peB + kk);
      pb.v[0] = ppb[0]; pb.v[1] = ppb[1];
    }
    if (f) {
      U ua, ub;
      const uint4* qa = reinterpret_cast<const uint4*>(hA16 + kk);
      ua.v[0] = qa[0]; ua.v[1] = qa[1];
      const uint4* qb = reinterpret_cast<const uint4*>(hB16 + kk);
      ub.v[0] = qb[0]; ub.v[1] = qb[1];
      for (int e = 0; e < 16; e++) {
        wha.u[e] = ua.u[e];
        whb.u[e] = ub.u[e];
        wxa.u[e] = f2b(b2f(ua.u[e]) + b2f(pa.u[e]));
        wxb.u[e] = f2b(b2f(ub.u[e]) + b2f(pb.u[e]));
      }
    } else {
      float fa[16], fb[16];
      const float4* qa = reinterpret_cast<const float4*>(hA32 + kk);
      const float4* qb = reinterpret_cast<const float4*>(hB32 + kk);
      for (int e = 0; e < 4; e++) {
        float4 va = qa[e], vb = qb[e];
        fa[4 * e + 0] = va.x; fa[4 * e + 1] = va.y; fa[4 * e + 2] = va.z; fa[4 * e + 3] = va.w;
        fb[4 * e + 0] = vb.x; fb[4 * e + 1] = vb.y; fb[4 * e + 2] = vb.z; fb[4 * e + 3] = vb.w;
      }
      for (int e = 0; e < 16; e++) {
        wha.u[e] = f2b(fa[e]);
        whb.u[e] = f2b(fb[e]);
        wxa.u[e] = f2b(fa[e] + b2f(pa.u[e]));
        wxb.u[e] = f2b(fb[e] + b2f(pb.u[e]));
      }
    }
    {
      uint4* d0 = reinterpret_cast<uint4*>(&sXa[sr * 40 + sc]);
      d0[0] = wxa.v[0]; d0[1] = wxa.v[1];
      uint4* d1 = reinterpret_cast<uint4*>(&sHa[sr * 40 + sc]);
      d1[0] = wha.v[0]; d1[1] = wha.v[1];
      uint4* d2 = reinterpret_cast<uint4*>(&sXb[sr * 40 + sc]);
      d2[0] = wxb.v[0]; d2[1] = wxb.v[1];
      uint4* d3 = reinterpret_cast<uint4*>(&sHb[sr * 40 + sc]);
      d3[0] = whb.v[0]; d3[1] = whb.v[1];
    }
    __syncthreads();

    bf16x8 bX[4], bH[4];
    for (int j = 0; j < 4; j++) {
      int dr = wc + j * 16 + fr;
      bX[j] = *reinterpret_cast<const bf16x8*>(&sXb[dr * 40 + fk]);
      bH[j] = *reinterpret_cast<const bf16x8*>(&sHb[dr * 40 + fk]);
    }
    for (int i = 0; i < 4; i++) {
      int cr = wr + i * 16 + fr;
      bf16x8 aX = *reinterpret_cast<const bf16x8*>(&sXa[cr * 40 + fk]);
      bf16x8 aH = *reinterpret_cast<const bf16x8*>(&sHa[cr * 40 + fk]);
      for (int j = 0; j < 4; j++) {
        acc1[i][j] = __builtin_amdgcn_mfma_f32_16x16x32_bf16(aX, bX[j], acc1[i][j], 0, 0, 0);
        acc2[i][j] = __builtin_amdgcn_mfma_f32_16x16x32_bf16(aH, bH[j], acc2[i][j], 0, 0, 0);
      }
    }
    __syncthreads();
  }

  const float invM = 1.0f / 1024.0f;
  const float invM2 = invM * invM;
  const float* gb = gate + b * C_N;
  const float* rxb = rx + b * C_N;
  const float* rbb = rb + b * C_N;
  for (int i = 0; i < 4; i++) {
    for (int r = 0; r < 4; r++) {
      int c = cblk + wr + i * 16 + (lane >> 4) * 4 + r;
      float gc = gb[c], rxc = rxb[c], rbc = rbb[c];
      for (int j = 0; j < 4; j++) {
        int d = dblk + wc + j * 16 + (lane & 15);
        float v = gc * gb[d] * (acc1[i][j][r] * invM - rxc * rxb[d] * invM2)
                + (acc2[i][j][r] * invM - rbc * rbb[d] * invM2);
        if (c == d) v += 1e-8f;
        size_t o = ((size_t)b * C_N + c) * C_N + d;
        if (f) ((unsigned short*)out)[o] = f2b(v);
        else   ((float*)out)[o] = v;
      }
    }
  }
}

extern "C" void kernel_launch(void* const* d_in, const int* in_sizes, int n_in,
                              void* d_out, int out_size, void* d_ws, size_t ws_size,
                              hipStream_t stream) {
  const void* h_in = d_in[0];
  const void* conv_w = d_in[1];
  const void* conv_b = d_in[2];

  char* ws = (char*)d_ws;
  int* flag = (int*)ws;
  int* mode = (int*)(ws + 64);
  float* pesum = (float*)(ws + 1024);
  float* rx = (float*)(ws + 4096);
  float* rb = rx + B_N * C_N;
  float* gate = rb + B_N * C_N;
  unsigned short* pe = (unsigned short*)(ws + (1 << 20));
  unsigned short* X = (unsigned short*)(ws + (2 << 20));
  size_t need = (size_t)(2 << 20) + 2ull * B_N * C_N * M_N + 4096;
  int wsOK = (ws_size >= need) ? 1 : 0;

  k_detect<<<1, 256, 0, stream>>>((const unsigned short*)h_in, flag);
  k_mode<<<1, 64, 0, stream>>>(flag, wsOK, mode);
  k_pe<<<(C_N * M_N) / 256, 256, 0, stream>>>(pe);
  k_pesum<<<C_N / 4, 256, 0, stream>>>(pe, pesum);
  k_sums<<<(B_N * C_N) / 4, 256, 0, stream>>>(h_in, flag, pesum, rx, rb);
  k_gate<<<(B_N * C_N) / 256, 256, 0, stream>>>(conv_w, conv_b, flag, rx, gate);
  k_prep<<<(B_N * C_N * M_N) / (8 * 256), 256, 0, stream>>>(h_in, pe, mode, X);
  dim3 g(C_N / 128, C_N / 128, B_N);
  k_cov2<<<g, 256, 0, stream>>>(X, h_in, mode, rx, rb, gate, d_out);
  k_cov<<<g, 256, 0, stream>>>(h_in, pe, flag, mode, rx, rb, gate, d_out);
}

// Round 3
// 373.486 us; speedup vs baseline: 1.0172x; 1.0004x over previous
//
#include <hip/hip_runtime.h>
#include <hip/hip_bf16.h>
#include <math.h>

#define B_N 64
#define C_N 512
#define M_N 1024

typedef __attribute__((ext_vector_type(8))) short bf16x8;
typedef __attribute__((ext_vector_type(4))) float f32x4;
typedef __attribute__((ext_vector_type(16))) float f32x16;

__device__ __forceinline__ float b2f(unsigned short u) {
  unsigned int x = ((unsigned int)u) << 16;
  return __builtin_bit_cast(float, x);
}
__device__ __forceinline__ unsigned short f2b(float f) {
  unsigned int x = __builtin_bit_cast(unsigned int, f);
  unsigned int lsb = (x >> 16) & 1u;
  x += 0x7fffu + lsb;
  return (unsigned short)(x >> 16);
}
__device__ __forceinline__ float bround(float f) { return b2f(f2b(f)); }

// async global->LDS, 16B per lane; LDS dest = wave-uniform base + lane*16.
// generic->as(3) via uintptr truncation (CK-style; LDS aperture is 4GB-aligned).
typedef __attribute__((address_space(1))) const unsigned int gas_uint;
typedef __attribute__((address_space(3))) unsigned int las_uint;
__device__ __forceinline__ void async_ld(const void* g, const void* l) {
  __builtin_amdgcn_global_load_lds((gas_uint*)(uintptr_t)g,
                                   (las_uint*)(unsigned int)(uintptr_t)l, 16, 0, 0);
}

// ---------- dtype detection ----------
__global__ void k_detect(const unsigned short* __restrict__ p, int* __restrict__ flag) {
  unsigned short u = p[threadIdx.x];
  int e = (u >> 7) & 0xff;
  int pl = (u == 0) || (e >= 110 && e <= 134);
  int cnt = __syncthreads_count(pl);
  if (threadIdx.x == 0) *flag = (cnt >= 208) ? 1 : 0;  // 1 = bf16, 0 = fp32
}

__global__ void k_mode(const int* __restrict__ flag, int wsOK, int* __restrict__ mode) {
  if (threadIdx.x == 0) *mode = (*flag == 1 && wsOK) ? 1 : 0;
}

// ---------- positional embedding, bf16 [C][M] ----------
__global__ void k_pe(unsigned short* __restrict__ pe) {
  int idx = blockIdx.x * 256 + threadIdx.x;
  int c = idx >> 10, m = idx & 1023;
  float freq = expf((float)(c & ~1) * (-9.210340371976184f / 512.0f));
  float ang = (float)m * freq;
  float v = (c & 1) ? cosf(ang) : sinf(ang);
  pe[idx] = f2b(v);
}

// ---------- per-row sums of pe (fp32) ----------
__global__ void k_pesum(const unsigned short* __restrict__ pe, float* __restrict__ pesum) {
  int lane = threadIdx.x & 63;
  int row = blockIdx.x * 4 + (threadIdx.x >> 6);  // 512 rows
  float s = 0.f;
  const uint4* p = (const uint4*)(pe + (size_t)row * M_N);
  for (int j = 0; j < 2; j++) {
    union { uint4 v; unsigned short u[8]; } a; a.v = p[j * 64 + lane];
    for (int k = 0; k < 8; k++) s += b2f(a.u[k]);
  }
  for (int off = 32; off; off >>= 1) s += __shfl_down(s, off);
  if (lane == 0) pesum[row] = s;
}

// ---------- row sums of h (vectorized); rx = rb + pesum[c] ----------
__global__ void k_sums(const void* __restrict__ hin, const int* __restrict__ flag,
                       const float* __restrict__ pesum, float* __restrict__ rx,
                       float* __restrict__ rb) {
  int lane = threadIdx.x & 63;
  int row = blockIdx.x * 4 + (threadIdx.x >> 6);  // [0, B*C)
  int f = *flag;
  float s = 0.f;
  if (f) {
    const uint4* h = (const uint4*)((const unsigned short*)hin + (size_t)row * M_N);
    for (int j = 0; j < 2; j++) {
      union { uint4 v; unsigned short u[8]; } a; a.v = h[j * 64 + lane];
      for (int k = 0; k < 8; k++) s += b2f(a.u[k]);
    }
  } else {
    const float4* h = (const float4*)((const float*)hin + (size_t)row * M_N);
    for (int j = 0; j < 4; j++) {
      float4 v = h[j * 64 + lane];
      s += v.x + v.y + v.z + v.w;
    }
  }
  for (int off = 32; off; off >>= 1) s += __shfl_down(s, off);
  if (lane == 0) { rb[row] = s; rx[row] = s + pesum[row & (C_N - 1)]; }
}

// ---------- gate ----------
__global__ void k_gate(const void* __restrict__ wp, const void* __restrict__ bp,
                       const int* __restrict__ flag, const float* __restrict__ rx,
                       float* __restrict__ gate) {
  int idx = blockIdx.x * 256 + threadIdx.x;  // [0, B*C)
  int b = idx >> 9, c = idx & (C_N - 1);
  int f = *flag;
  float acc = 0.f;
  for (int k = 0; k < 5; ++k) {
    int cc = c + k - 2;
    if (cc < 0 || cc >= C_N) continue;
    float y = rx[b * C_N + cc] * (1.0f / 1024.0f);
    float w;
    if (f) { y = bround(y); w = b2f(((const unsigned short*)wp)[c * 5 + k]); }
    else   { w = ((const float*)wp)[c * 5 + k]; }
    acc += y * w;
  }
  float bias = f ? b2f(((const unsigned short*)bp)[c]) : ((const float*)bp)[c];
  float s = f ? bround(bround(acc) + bias) : (acc + bias);
  float g = 1.0f / (1.0f + expf(-s));
  if (f) g = bround(g);
  gate[idx] = g;
}

// ---------- X = bf16(h + pe) for a CHUNK of nb batches (fast path only) -----
__global__ void k_prep(const void* __restrict__ hchunk, const unsigned short* __restrict__ pe,
                       const int* __restrict__ mode, unsigned short* __restrict__ X) {
  if (*mode != 1) return;
  size_t e = ((size_t)blockIdx.x * 256 + threadIdx.x) * 8;
  int cm = (int)(e & ((size_t)C_N * M_N - 1));
  union { uint4 v; unsigned short u[8]; } a, p, r;
  a.v = *(const uint4*)((const unsigned short*)hchunk + e);
  p.v = *(const uint4*)(pe + cm);
  for (int k = 0; k < 8; k++) r.u[k] = f2b(b2f(a.u[k]) + b2f(p.u[k]));
  *(uint4*)(X + e) = r.v;
}

// ---------- FAST cov: dual-Gram via 32x32x16 MFMA + global_load_lds ----------
// Operates on one chunk of batches; all pointers pre-offset to the chunk.
// LDS tiles [128][32] bf16, unpadded. XOR swizzle: 16B chunk at (row, pcol)
// holds data (row, pcol ^ ((row>>1)&3)).
__global__ __launch_bounds__(256, 2)
void k_cov2(const unsigned short* __restrict__ X, const void* __restrict__ hin,
            const int* __restrict__ mode, const float* __restrict__ rx,
            const float* __restrict__ rb, const float* __restrict__ gate,
            void* __restrict__ out) {
  if (*mode != 1) return;
  __shared__ unsigned short tiles[4][128 * 32];  // Xa, Ha, Xb, Hb = 32 KB

  const unsigned short* H = (const unsigned short*)hin;
  int t = threadIdx.x;
  int lane = t & 63, w = t >> 6;
  int b = blockIdx.z;  // batch within chunk
  int cblk = blockIdx.y * 128, dblk = blockIdx.x * 128;

  // staging: wave w owns tile w (0:Xa 1:Ha 2:Xb 3:Hb)
  const unsigned short* src = (w & 1) ? H : X;
  int rowbase = (w & 2) ? dblk : cblk;
  int gcol = (lane & 3) ^ ((lane >> 3) & 3);  // swizzled source chunk
  const unsigned short* gp = src + (size_t)b * (C_N * M_N)
                           + (size_t)(rowbase + (lane >> 2)) * M_N + gcol * 8;

  int wr = (w >> 1) * 64, wc = (w & 1) * 64;  // 64x64 quadrant
  int fr = lane & 31, L5 = lane >> 5;
  int sw = (fr >> 1) & 3;

  f32x16 a1[2][2], a2[2][2];
  for (int i = 0; i < 2; i++)
    for (int j = 0; j < 2; j++)
      for (int r = 0; r < 16; r++) { a1[i][j][r] = 0.f; a2[i][j][r] = 0.f; }

  for (int kk = 0; kk < M_N; kk += 32) {
    const unsigned short* g0 = gp + kk;
    for (int g = 0; g < 8; g++)
      async_ld(g0 + (size_t)g * (16 * M_N), &tiles[w][g * 512]);
    __syncthreads();

    for (int ks = 0; ks < 2; ks++) {
      int kc = (ks * 2 + L5);
      bf16x8 aX[2], aH[2], bX[2], bH[2];
      for (int i = 0; i < 2; i++) {
        int R = wr + i * 32 + fr;
        int off = R * 32 + (kc ^ sw) * 8;
        aX[i] = *(const bf16x8*)&tiles[0][off];
        aH[i] = *(const bf16x8*)&tiles[1][off];
      }
      for (int j = 0; j < 2; j++) {
        int D = wc + j * 32 + fr;
        int off = D * 32 + (kc ^ sw) * 8;
        bX[j] = *(const bf16x8*)&tiles[2][off];
        bH[j] = *(const bf16x8*)&tiles[3][off];
      }
      for (int i = 0; i < 2; i++)
        for (int j = 0; j < 2; j++) {
          a1[i][j] = __builtin_amdgcn_mfma_f32_32x32x16_bf16(aX[i], bX[j], a1[i][j], 0, 0, 0);
          a2[i][j] = __builtin_amdgcn_mfma_f32_32x32x16_bf16(aH[i], bH[j], a2[i][j], 0, 0, 0);
        }
    }
    __syncthreads();
  }

  // epilogue: C/D map (32x32): col = lane&31, row = (reg&3)+8*(reg>>2)+4*L5
  const float invM = 1.0f / 1024.0f, invM2 = invM * invM;
  const float* gb = gate + b * C_N;
  const float* rxb = rx + b * C_N;
  const float* rbb = rb + b * C_N;
  unsigned short* o16 = (unsigned short*)out;
  for (int i = 0; i < 2; i++)
    for (int j = 0; j < 2; j++) {
      int d = dblk + wc + j * 32 + (lane & 31);
      float gd = gb[d], rxd = rxb[d], rbd = rbb[d];
      for (int reg = 0; reg < 16; reg++) {
        int row = (reg & 3) + 8 * (reg >> 2) + 4 * L5;
        int c = cblk + wr + i * 32 + row;
        float v = gb[c] * gd * (a1[i][j][reg] * invM - rxb[c] * rxd * invM2)
                + (a2[i][j][reg] * invM - rbb[c] * rbd * invM2);
        if (c == d) v += 1e-8f;
        o16[((size_t)b * C_N + c) * C_N + d] = f2b(v);
      }
    }
}

// ---------- SLOW cov (fallback: fp32 input or tiny ws) ----------
__global__ __launch_bounds__(256, 2)
void k_cov(const void* __restrict__ hin, const unsigned short* __restrict__ pe,
           const int* __restrict__ flag, const int* __restrict__ mode,
           const float* __restrict__ rx, const float* __restrict__ rb,
           const float* __restrict__ gate, void* __restrict__ out) {
  if (*mode != 0) return;
  __shared__ unsigned short sXa[128 * 40];
  __shared__ unsigned short sHa[128 * 40];
  __shared__ unsigned short sXb[128 * 40];
  __shared__ unsigned short sHb[128 * 40];

  int t = threadIdx.x;
  int b = blockIdx.z;
  int cblk = blockIdx.y * 128, dblk = blockIdx.x * 128;
  int f = *flag;
  int lane = t & 63, wave = t >> 6;
  int wr = (wave >> 1) * 64, wc = (wave & 1) * 64;
  int fr = lane & 15, fk = (lane >> 4) * 8;
  int sr = t >> 1, sc = (t & 1) * 16;

  f32x4 acc1[4][4], acc2[4][4];
  const f32x4 z = {0.f, 0.f, 0.f, 0.f};
  for (int i = 0; i < 4; i++)
    for (int j = 0; j < 4; j++) { acc1[i][j] = z; acc2[i][j] = z; }

  const size_t hb0 = (size_t)b * C_N * M_N;
  const unsigned short* peA = pe + (size_t)(cblk + sr) * M_N + sc;
  const unsigned short* peB = pe + (size_t)(dblk + sr) * M_N + sc;
  const unsigned short* hA16 = (const unsigned short*)hin + hb0 + (size_t)(cblk + sr) * M_N + sc;
  const unsigned short* hB16 = (const unsigned short*)hin + hb0 + (size_t)(dblk + sr) * M_N + sc;
  const float* hA32 = (const float*)hin + hb0 + (size_t)(cblk + sr) * M_N + sc;
  const float* hB32 = (const float*)hin + hb0 + (size_t)(dblk + sr) * M_N + sc;

  union U { uint4 v[2]; unsigned short u[16]; };

  for (int kk = 0; kk < M_N; kk += 32) {
    U pa, pb, wxa, wha, wxb, whb;
    {
      const uint4* ppa = reinterpret_cast<const uint4*>(peA + kk);
      pa.v[0] = ppa[0]; pa.v[1] = ppa[1];
      const uint4* ppb = reinterpret_cast<const uint4*>(peB + kk);
      pb.v[0] = ppb[0]; pb.v[1] = ppb[1];
    }
    if (f) {
      U ua, ub;
      const uint4* qa = reinterpret_cast<const uint4*>(hA16 + kk);
      ua.v[0] = qa[0]; ua.v[1] = qa[1];
      const uint4* qb = reinterpret_cast<const uint4*>(hB16 + kk);
      ub.v[0] = qb[0]; ub.v[1] = qb[1];
      for (int e = 0; e < 16; e++) {
        wha.u[e] = ua.u[e];
        whb.u[e] = ub.u[e];
        wxa.u[e] = f2b(b2f(ua.u[e]) + b2f(pa.u[e]));
        wxb.u[e] = f2b(b2f(ub.u[e]) + b2f(pb.u[e]));
      }
    } else {
      float fa[16], fb[16];
      const float4* qa = reinterpret_cast<const float4*>(hA32 + kk);
      const float4* qb = reinterpret_cast<const float4*>(hB32 + kk);
      for (int e = 0; e < 4; e++) {
        float4 va = qa[e], vb = qb[e];
        fa[4 * e + 0] = va.x; fa[4 * e + 1] = va.y; fa[4 * e + 2] = va.z; fa[4 * e + 3] = va.w;
        fb[4 * e + 0] = vb.x; fb[4 * e + 1] = vb.y; fb[4 * e + 2] = vb.z; fb[4 * e + 3] = vb.w;
      }
      for (int e = 0; e < 16; e++) {
        wha.u[e] = f2b(fa[e]);
        whb.u[e] = f2b(fb[e]);
        wxa.u[e] = f2b(fa[e] + b2f(pa.u[e]));
        wxb.u[e] = f2b(fb[e] + b2f(pb.u[e]));
      }
    }
    {
      uint4* d0 = reinterpret_cast<uint4*>(&sXa[sr * 40 + sc]);
      d0[0] = wxa.v[0]; d0[1] = wxa.v[1];
      uint4* d1 = reinterpret_cast<uint4*>(&sHa[sr * 40 + sc]);
      d1[0] = wha.v[0]; d1[1] = wha.v[1];
      uint4* d2 = reinterpret_cast<uint4*>(&sXb[sr * 40 + sc]);
      d2[0] = wxb.v[0]; d2[1] = wxb.v[1];
      uint4* d3 = reinterpret_cast<uint4*>(&sHb[sr * 40 + sc]);
      d3[0] = whb.v[0]; d3[1] = whb.v[1];
    }
    __syncthreads();

    bf16x8 bX[4], bH[4];
    for (int j = 0; j < 4; j++) {
      int dr = wc + j * 16 + fr;
      bX[j] = *reinterpret_cast<const bf16x8*>(&sXb[dr * 40 + fk]);
      bH[j] = *reinterpret_cast<const bf16x8*>(&sHb[dr * 40 + fk]);
    }
    for (int i = 0; i < 4; i++) {
      int cr = wr + i * 16 + fr;
      bf16x8 aX = *reinterpret_cast<const bf16x8*>(&sXa[cr * 40 + fk]);
      bf16x8 aH = *reinterpret_cast<const bf16x8*>(&sHa[cr * 40 + fk]);
      for (int j = 0; j < 4; j++) {
        acc1[i][j] = __builtin_amdgcn_mfma_f32_16x16x32_bf16(aX, bX[j], acc1[i][j], 0, 0, 0);
        acc2[i][j] = __builtin_amdgcn_mfma_f32_16x16x32_bf16(aH, bH[j], acc2[i][j], 0, 0, 0);
      }
    }
    __syncthreads();
  }

  const float invM = 1.0f / 1024.0f;
  const float invM2 = invM * invM;
  const float* gb = gate + b * C_N;
  const float* rxb = rx + b * C_N;
  const float* rbb = rb + b * C_N;
  for (int i = 0; i < 4; i++) {
    for (int r = 0; r < 4; r++) {
      int c = cblk + wr + i * 16 + (lane >> 4) * 4 + r;
      float gc = gb[c], rxc = rxb[c], rbc = rbb[c];
      for (int j = 0; j < 4; j++) {
        int d = dblk + wc + j * 16 + (lane & 15);
        float v = gc * gb[d] * (acc1[i][j][r] * invM - rxc * rxb[d] * invM2)
                + (acc2[i][j][r] * invM - rbc * rbb[d] * invM2);
        if (c == d) v += 1e-8f;
        size_t o = ((size_t)b * C_N + c) * C_N + d;
        if (f) ((unsigned short*)out)[o] = f2b(v);
        else   ((float*)out)[o] = v;
      }
    }
  }
}

extern "C" void kernel_launch(void* const* d_in, const int* in_sizes, int n_in,
                              void* d_out, int out_size, void* d_ws, size_t ws_size,
                              hipStream_t stream) {
  const void* h_in = d_in[0];
  const void* conv_w = d_in[1];
  const void* conv_b = d_in[2];

  char* ws = (char*)d_ws;
  int* flag = (int*)ws;
  int* mode = (int*)(ws + 64);
  float* pesum = (float*)(ws + 128);
  float* rx = (float*)(ws + 4096);                        // 128 KB
  float* rb = rx + B_N * C_N;                             // 128 KB
  float* gate = rb + B_N * C_N;                           // 128 KB
  unsigned short* pe = (unsigned short*)(ws + (512 << 10)); // 1 MB
  unsigned short* X = (unsigned short*)(ws + (1536 << 10)); // chunk buffer

  const size_t batch_bytes = (size_t)C_N * M_N * 2;       // 1 MB per batch
  size_t base = (size_t)(1536 << 10);
  int nb = 0;
  if (ws_size > base + batch_bytes) {
    size_t fit = (ws_size - base) / batch_bytes;
    for (int cand = 64; cand >= 1; cand >>= 1)
      if ((size_t)cand <= fit) { nb = cand; break; }
  }
  int wsOK = (nb >= 1) ? 1 : 0;

  k_detect<<<1, 256, 0, stream>>>((const unsigned short*)h_in, flag);
  k_mode<<<1, 64, 0, stream>>>(flag, wsOK, mode);
  k_pe<<<(C_N * M_N) / 256, 256, 0, stream>>>(pe);
  k_pesum<<<C_N / 4, 256, 0, stream>>>(pe, pesum);
  k_sums<<<(B_N * C_N) / 4, 256, 0, stream>>>(h_in, flag, pesum, rx, rb);
  k_gate<<<(B_N * C_N) / 256, 256, 0, stream>>>(conv_w, conv_b, flag, rx, gate);

  if (wsOK) {
    for (int c0 = 0; c0 < B_N; c0 += nb) {
      const unsigned short* hc = (const unsigned short*)h_in + (size_t)c0 * C_N * M_N;
      k_prep<<<nb * 256, 256, 0, stream>>>(hc, pe, mode, X);
      dim3 g(C_N / 128, C_N / 128, nb);
      k_cov2<<<g, 256, 0, stream>>>(X, hc, mode,
                                    rx + c0 * C_N, rb + c0 * C_N, gate + c0 * C_N,
                                    (unsigned short*)d_out + (size_t)c0 * C_N * C_N);
    }
  }
  dim3 g(C_N / 128, C_N / 128, B_N);
  k_cov<<<g, 256, 0, stream>>>(h_in, pe, flag, mode, rx, rb, gate, d_out);
}